// Round 14
// baseline (80.410 us; speedup 1.0000x reference)
//
#include <hip/hip_runtime.h>
#include <math.h>

#define WPB 4                 // waves per block; ONE row per full 64-lane wave
#define BLOCK_T (WPB * 64)
#define GX 4
#define GY 4
#define GZ 16
#define NCELL (GX * GY * GZ)  // 256 cells; z fastest => z-columns are CSR-contiguous
#define BUILD_T 1024
#define CAP 64                // candidate cap per row
#define CELL_LDS 8192
#define IDMASK 8191ull        // low 13 bits of sort key hold the point id (Mv < 8192)

__device__ __forceinline__ float fast_cbrt(float x) {
    // x > 0. Bit-hack seed + 1 Newton step (~0.2% rel) — count ~ h^3 -> ~0.6% err.
    float y = __int_as_float(0x2a514067 + __float_as_int(x) / 3);
    y = 0.33333333f * (2.0f * y + x * __frcp_rn(y * y));
    return y;
}

__device__ __forceinline__ int cell_of(float x, float y, float z) {
    int cx = (int)floorf((x + 1.0f) * (GX * 0.5f)); cx = min(max(cx, 0), GX - 1);
    int cy = (int)floorf((y + 1.0f) * (GY * 0.5f)); cy = min(max(cy, 0), GY - 1);
    int cz = (int)floorf((z + 1.0f) * (GZ * 0.5f)); cz = min(max(cz, 0), GZ - 1);
    return (cx * GY + cy) * GZ + cz;
}

// Single-block fused grid build: LDS hist -> shuffle scan (256 cells) -> scatter.
__global__ __launch_bounds__(BUILD_T)
void k_build(const float* __restrict__ vp, float4* __restrict__ pts4,
             int* __restrict__ off, int Mv)
{
    __shared__ int s_cnt[NCELL];
    __shared__ int s_wsum[4];
    __shared__ unsigned short s_cell[CELL_LDS];
    const int t = threadIdx.x, lane = t & 63, w = t >> 6;
    if (t < NCELL) s_cnt[t] = 0;
    __syncthreads();
    for (int j = t; j < Mv; j += BUILD_T) {
        const int c = cell_of(vp[3*j], vp[3*j+1], vp[3*j+2]);
        if (j < CELL_LDS) s_cell[j] = (unsigned short)c;
        atomicAdd(&s_cnt[c], 1);
    }
    __syncthreads();
    int c = 0, v = 0;
    if (t < NCELL) {                         // waves 0..3 complete -> wave-uniform
        c = s_cnt[t];
        v = c;                               // intra-wave inclusive shuffle scan
        #pragma unroll
        for (int s = 1; s < 64; s <<= 1) {
            const int u = __shfl_up(v, s, 64);
            if (lane >= s) v += u;
        }
        if (lane == 63) s_wsum[w] = v;
    }
    __syncthreads();
    if (t < 64) {
        int x = (lane < 4) ? s_wsum[lane] : 0;
        #pragma unroll
        for (int s = 1; s < 4; s <<= 1) {
            const int u = __shfl_up(x, s, 64);
            if (lane >= s) x += u;
        }
        if (lane < 4) s_wsum[lane] = x;
    }
    __syncthreads();
    if (t < NCELL) {
        const int start = v + ((w > 0) ? s_wsum[w - 1] : 0) - c;
        off[t] = start;
        if (t == NCELL - 1) off[NCELL] = start + c;
        s_cnt[t] = start;                    // becomes running cursor
    }
    __syncthreads();
    for (int j = t; j < Mv; j += BUILD_T) {
        const float x = vp[3*j], y = vp[3*j+1], z = vp[3*j+2];
        const int cell = (j < CELL_LDS) ? (int)s_cell[j] : cell_of(x, y, z);
        const int pos = atomicAdd(&s_cnt[cell], 1);
        pts4[pos] = make_float4(x, y, z, __int_as_float(j));
    }
}

// One full wave per output row; per-column Z-TRIM cuts gathered points ~30%
// (box z-extent -> per-column slab sqrt(tauL - dxy_min^2)).
// Rows [0, Nq): per-query Voronoi edge-distance min     -> out[row]
// Rows [Nq, Nq+Mv): repulsion, wave r processes pts4[r] (cell-sorted order)
//                   -> out[Nq + orig_id*10 + rank-1]
__global__ __launch_bounds__(BLOCK_T)
void voronoi_kernel(const float* __restrict__ queries,
                    const float4* __restrict__ pts4,
                    const int* __restrict__ off,
                    float* __restrict__ out,
                    int Nq, int Mv)
{
    __shared__ float4             s_c[WPB][CAP];   // candidate coords + id
    __shared__ unsigned long long s_k[WPB][CAP];   // packed sort keys

    const int lane = threadIdx.x & 63;
    const int wv   = threadIdx.x >> 6;
    const int row  = blockIdx.x * WPB + wv;
    const int total = Nq + Mv;
    if (row >= total) return;             // wave-uniform

    const bool isq = (row < Nq);
    float qx, qy, qz;
    int outj = 0;
    if (isq) {
        const float* src = queries + 3 * row;
        qx = src[0]; qy = src[1]; qz = src[2];
    } else {
        const float4 me = pts4[row - Nq];  // cell-sorted copy of vpoints
        qx = me.x; qy = me.y; qz = me.z;
        outj = __float_as_int(me.w);       // original vpoint index for output
    }

    // ---- adaptive radius h: target ~24 strict candidates, boundary-aware.
    // ONE fixed-point refine: h is just a seed; rescan window [11,64] covers.
    const float rho = (float)Mv * 0.125f;
    const float Tt  = 24.0f * 6.0f / (3.14159265f * rho);
    float h = 0.5f * fast_cbrt(Tt);
    {
        float ex = fminf(qx + h, 1.0f) - fmaxf(qx - h, -1.0f);
        float ey = fminf(qy + h, 1.0f) - fmaxf(qy - h, -1.0f);
        float ez = fminf(qz + h, 1.0f) - fmaxf(qz - h, -1.0f);
        h *= fast_cbrt(Tt * __frcp_rn(ex * ey * ez));
    }

    // ---- grid-pruned scan, per-column z-trim; strict count post-hoc ----
    // Containment: any true top-11 point has fp64 d2 < tau(1+2^-40) < tauL;
    // its column has dxy_min^2 <= d2 < tauL (not skipped) and |dz| < zr =
    // sqrt(tauL - dxy_min^2) (+1e-6 pad, outward cell rounding) -> scanned;
    // fp32 d2 < tauL (MARGIN >> fp32 err) -> admitted. cntL<=CAP -> none dropped.
    const float MARGIN = 2e-5f;
    float4 c4 = make_float4(0.f, 0.f, 0.f, 0.f);
    unsigned long long key = ~0ull;
    int cntL = 0;
    const float qzs = (qz + 1.0f) * (GZ * 0.5f);   // z index scale hoisted
    for (int attempt = 0; attempt < 16; ++attempt) {
        cntL = 0;
        const float tau  = h * h;
        const float tauL = tau + MARGIN;
        int ix0 = (int)floorf((qx - h + 1.0f) * (GX * 0.5f)); ix0 = min(max(ix0, 0), GX - 1);
        int ix1 = (int)floorf((qx + h + 1.0f) * (GX * 0.5f)); ix1 = min(max(ix1, 0), GX - 1);
        int iy0 = (int)floorf((qy - h + 1.0f) * (GY * 0.5f)); iy0 = min(max(iy0, 0), GY - 1);
        int iy1 = (int)floorf((qy + h + 1.0f) * (GY * 0.5f)); iy1 = min(max(iy1, 0), GY - 1);
        // wave-uniform -> SALU loop control
        ix0 = __builtin_amdgcn_readfirstlane(ix0);
        ix1 = __builtin_amdgcn_readfirstlane(ix1);
        iy0 = __builtin_amdgcn_readfirstlane(iy0);
        iy1 = __builtin_amdgcn_readfirstlane(iy1);

        for (int cx = ix0; cx <= ix1; ++cx) {
            const float clx = -1.0f + 0.5f * (float)cx;          // column x-rect
            const float dxm = fmaxf(0.0f, fmaxf(clx - qx, qx - (clx + 0.5f)));
            for (int cy = iy0; cy <= iy1; ++cy) {
                const float cly = -1.0f + 0.5f * (float)cy;      // column y-rect
                const float dym = fmaxf(0.0f, fmaxf(cly - qy, qy - (cly + 0.5f)));
                const float rem = tauL - dxm * dxm - dym * dym;
                if (rem <= 0.0f) continue;   // column misses ball (wave-uniform)
                const float zr8 = sqrtf(rem) * (GZ * 0.5f) + 1e-5f;
                int iz0 = (int)floorf(qzs - zr8); iz0 = min(max(iz0, 0), GZ - 1);
                int iz1 = (int)floorf(qzs + zr8); iz1 = min(max(iz1, 0), GZ - 1);
                iz0 = __builtin_amdgcn_readfirstlane(iz0);
                iz1 = __builtin_amdgcn_readfirstlane(iz1);
                const int colbase = (cx * GY + cy) * GZ;
                const int s0 = __builtin_amdgcn_readfirstlane(off[colbase + iz0]);
                const int e0 = __builtin_amdgcn_readfirstlane(off[colbase + iz1 + 1]);
                for (int p0 = s0; p0 < e0; p0 += 64) {  // wave-uniform trip count
                    const int p = p0 + lane;
                    bool pl = false;
                    float4 pt;
                    if (p < e0) {
                        pt = pts4[p];
                        const float dx = qx - pt.x, dy = qy - pt.y, dz = qz - pt.z;
                        const float d2 = fmaf(dx, dx, fmaf(dy, dy, dz * dz));
                        pl = (d2 < tauL);
                    }
                    const unsigned long long mL = __ballot(pl);
                    if (pl) {
                        const int o = cntL + (int)__popcll(mL & ((1ULL << lane) - 1ULL));
                        if (o < CAP) s_c[wv][o] = pt;
                    }
                    cntL += (int)__popcll(mL);
                }
            }
        }
        if (cntL > CAP) { h *= 0.80f; continue; }       // overflow -> shrink

        // packed key: fp64 d2 bits, low 13 mantissa bits = id (keys unique)
        key = ~0ull;
        if (lane < cntL) {
            c4 = s_c[wv][lane];
            const double dx = (double)qx - (double)c4.x;
            const double dy = (double)qy - (double)c4.y;
            const double dz = (double)qz - (double)c4.z;
            const double d2 = fma(dx, dx, fma(dy, dy, dz * dz));
            key = (__double_as_longlong(d2) & ~IDMASK)
                | (unsigned long long)(unsigned)__float_as_int(c4.w);
        }
        const unsigned long long tauKey =
            (unsigned long long)__double_as_longlong((double)tau) & ~IDMASK;
        const int cntS = (int)__popcll(__ballot(key < tauKey));
        if (cntS >= 11) break;                          // wave-uniform
        h *= 1.35f;                                     // too few -> grow
    }
    cntL = min(cntL, CAP);                  // safety (attempt exhaustion only)

    // ---- rank-by-count: rank = #{keys < mine}; no dependent shuffle chain ----
    s_k[wv][lane] = key;
    int rank = 0;
    for (int c = 0; c < cntL; ++c)          // wave-uniform; broadcast ds_read
        rank += (s_k[wv][c] < key) ? 1 : 0;
    // real lanes get unique ranks 0..cntL-1; pad lanes rank >= cntL >= 11.

    if (isq) {
        // p0 = rank-0 candidate; edges = ranks 1..10 (set-min, order-free)
        const unsigned long long m0 = __ballot(rank == 0);
        const int l0 = (int)__ffsll(m0) - 1;
        const float p0x = __shfl(c4.x, l0, 64);
        const float p0y = __shfl(c4.y, l0, 64);
        const float p0z = __shfl(c4.z, l0, 64);
        float sq = INFINITY;
        if (rank >= 1 && rank <= 10) {
            const float ex = c4.x - p0x, ey = c4.y - p0y, ez = c4.z - p0z;
            const float el = sqrtf(ex * ex + ey * ey + ez * ez);
            const float px = qx - p0x, py = qy - p0y, pz = qz - p0z;
            const float vl = (px * ex + py * ey + pz * ez) / el;
            const float t  = vl - 0.5f * el;
            sq = t * t;
        }
        #pragma unroll
        for (int s = 32; s > 0; s >>= 1) sq = fminf(sq, __shfl_xor(sq, s, 64));
        if (lane == 0) out[row] = sq;
    } else {
        if (rank >= 1 && rank <= 10) {
            const double d2s = __longlong_as_double((long long)(key & ~IDMASK));
            out[Nq + outj * 10 + (rank - 1)] = expf(-100.0f * (float)d2s) / 100.0f;
        }
    }
}

extern "C" void kernel_launch(void* const* d_in, const int* in_sizes, int n_in,
                              void* d_out, int out_size, void* d_ws, size_t ws_size,
                              hipStream_t stream) {
    const float* queries = (const float*)d_in[0];
    const float* vpoints = (const float*)d_in[1];
    float* out = (float*)d_out;
    const int Nq = in_sizes[0] / 3;
    const int Mv = in_sizes[1] / 3;

    // workspace layout: pts4[Mv] | off[NCELL+1]
    char* base = (char*)d_ws;
    float4* pts4 = (float4*)base;
    int* off = (int*)(base + (size_t)Mv * sizeof(float4));

    k_build<<<1, BUILD_T, 0, stream>>>(vpoints, pts4, off, Mv);

    const int total_rows = Nq + Mv;
    const int blocks = (total_rows + WPB - 1) / WPB;
    voronoi_kernel<<<blocks, BLOCK_T, 0, stream>>>(queries, pts4, off,
                                                   out, Nq, Mv);
}

// Round 15
// 78.674 us; speedup vs baseline: 1.0221x; 1.0221x over previous
//
#include <hip/hip_runtime.h>
#include <math.h>

#define WPB 4                 // waves per block; ONE row per full 64-lane wave
#define BLOCK_T (WPB * 64)
#define GX 4
#define GY 4
#define GZ 16
#define NCELL (GX * GY * GZ)  // 256 cells; z fastest => z-columns are CSR-contiguous
#define BUILD_T 1024
#define CAP 64                // candidate cap per row
#define IDMASK 8191ull        // low 13 bits of sort key hold the point id (Mv < 8192)

__device__ __forceinline__ float fast_cbrt(float x) {
    // x > 0. Bit-hack seed + 1 Newton step (~0.2% rel) — count ~ h^3 -> ~0.6% err.
    float y = __int_as_float(0x2a514067 + __float_as_int(x) / 3);
    y = 0.33333333f * (2.0f * y + x * __frcp_rn(y * y));
    return y;
}

__device__ __forceinline__ int cell_of(float x, float y, float z) {
    int cx = (int)floorf((x + 1.0f) * (GX * 0.5f)); cx = min(max(cx, 0), GX - 1);
    int cy = (int)floorf((y + 1.0f) * (GY * 0.5f)); cy = min(max(cy, 0), GY - 1);
    int cz = (int)floorf((z + 1.0f) * (GZ * 0.5f)); cz = min(max(cz, 0), GZ - 1);
    return (cx * GY + cy) * GZ + cz;
}

// Dispatch 1 (single block): LDS hist -> 2-barrier shuffle scan -> off[], cur[].
__global__ __launch_bounds__(BUILD_T)
void k_histscan(const float* __restrict__ vp, int* __restrict__ off,
                int* __restrict__ cur, int Mv)
{
    __shared__ int s_cnt[NCELL];
    __shared__ int s_wsum[4];
    const int t = threadIdx.x, lane = t & 63, w = t >> 6;
    if (t < NCELL) s_cnt[t] = 0;
    __syncthreads();
    for (int j = t; j < Mv; j += BUILD_T)
        atomicAdd(&s_cnt[cell_of(vp[3*j], vp[3*j+1], vp[3*j+2])], 1);
    __syncthreads();
    int c = 0, v = 0;
    if (t < NCELL) {                         // waves 0..3 complete -> wave-uniform
        c = s_cnt[t];
        v = c;                               // intra-wave inclusive shuffle scan
        #pragma unroll
        for (int s = 1; s < 64; s <<= 1) {
            const int u = __shfl_up(v, s, 64);
            if (lane >= s) v += u;
        }
        if (lane == 63) s_wsum[w] = v;
    }
    __syncthreads();
    if (t < 64) {
        int x = (lane < 4) ? s_wsum[lane] : 0;
        #pragma unroll
        for (int s = 1; s < 4; s <<= 1) {
            const int u = __shfl_up(x, s, 64);
            if (lane >= s) x += u;
        }
        if (lane < 4) s_wsum[lane] = x;
    }
    __syncthreads();
    if (t < NCELL) {
        const int start = v + ((w > 0) ? s_wsum[w - 1] : 0) - c;
        off[t] = start;
        cur[t] = start;
        if (t == NCELL - 1) off[NCELL] = start + c;
    }
}

// Dispatch 2 (parallel): scatter points into cell-sorted pts4.
__global__ void k_scatter(const float* __restrict__ vp, int* __restrict__ cur,
                          float4* __restrict__ pts4, int Mv)
{
    const int j = blockIdx.x * blockDim.x + threadIdx.x;
    if (j < Mv) {
        const float x = vp[3*j], y = vp[3*j+1], z = vp[3*j+2];
        const int pos = atomicAdd(&cur[cell_of(x, y, z)], 1);
        pts4[pos] = make_float4(x, y, z, __int_as_float(j));
    }
}

// One full wave per output row.  (R13 kernel, verbatim — best-known config.)
// Rows [0, Nq): per-query Voronoi edge-distance min     -> out[row]
// Rows [Nq, Nq+Mv): repulsion, wave r processes pts4[r] (cell-sorted order)
//                   -> out[Nq + orig_id*10 + rank-1]
__global__ __launch_bounds__(BLOCK_T)
void voronoi_kernel(const float* __restrict__ queries,
                    const float4* __restrict__ pts4,
                    const int* __restrict__ off,
                    float* __restrict__ out,
                    int Nq, int Mv)
{
    __shared__ float4             s_c[WPB][CAP];   // candidate coords + id
    __shared__ unsigned long long s_k[WPB][CAP];   // packed sort keys

    const int lane = threadIdx.x & 63;
    const int wv   = threadIdx.x >> 6;
    const int row  = blockIdx.x * WPB + wv;
    const int total = Nq + Mv;
    if (row >= total) return;             // wave-uniform

    const bool isq = (row < Nq);
    float qx, qy, qz;
    int outj = 0;
    if (isq) {
        const float* src = queries + 3 * row;
        qx = src[0]; qy = src[1]; qz = src[2];
    } else {
        const float4 me = pts4[row - Nq];  // cell-sorted copy of vpoints
        qx = me.x; qy = me.y; qz = me.z;
        outj = __float_as_int(me.w);       // original vpoint index for output
    }

    // ---- adaptive radius h: target ~24 strict candidates, boundary-aware.
    // ONE fixed-point refine only: h is just a seed; the rescan window [11,64]
    // guarantees correctness, so ~10-15% count error on boundary rows is fine.
    const float rho = (float)Mv * 0.125f;
    const float Tt  = 24.0f * 6.0f / (3.14159265f * rho);
    float h = 0.5f * fast_cbrt(Tt);
    {
        float ex = fminf(qx + h, 1.0f) - fmaxf(qx - h, -1.0f);
        float ey = fminf(qy + h, 1.0f) - fmaxf(qy - h, -1.0f);
        float ez = fminf(qz + h, 1.0f) - fmaxf(qz - h, -1.0f);
        h *= fast_cbrt(Tt * __frcp_rn(ex * ey * ez));
    }

    // ---- grid-pruned scan: ONE loose ballot/iter; strict count post-hoc ----
    // Containment: cntS = #{masked-fp64 d2 < tau} >= 11 proves the true top-11
    // all lie within h(1+2^-40) (inside scanned box) and under tauL (admitted);
    // cntL <= CAP proves none dropped. At target 24, P(rescan) ~ 1e-3, so the
    // in-loop key computation effectively runs once.
    const float MARGIN = 2e-5f;
    float4 c4 = make_float4(0.f, 0.f, 0.f, 0.f);
    unsigned long long key = ~0ull;
    int cntL = 0;
    for (int attempt = 0; attempt < 16; ++attempt) {
        cntL = 0;
        const float tau  = h * h;
        const float tauL = tau + MARGIN;
        int ix0 = (int)floorf((qx - h + 1.0f) * (GX * 0.5f)); ix0 = min(max(ix0, 0), GX - 1);
        int ix1 = (int)floorf((qx + h + 1.0f) * (GX * 0.5f)); ix1 = min(max(ix1, 0), GX - 1);
        int iy0 = (int)floorf((qy - h + 1.0f) * (GY * 0.5f)); iy0 = min(max(iy0, 0), GY - 1);
        int iy1 = (int)floorf((qy + h + 1.0f) * (GY * 0.5f)); iy1 = min(max(iy1, 0), GY - 1);
        int iz0 = (int)floorf((qz - h + 1.0f) * (GZ * 0.5f)); iz0 = min(max(iz0, 0), GZ - 1);
        int iz1 = (int)floorf((qz + h + 1.0f) * (GZ * 0.5f)); iz1 = min(max(iz1, 0), GZ - 1);
        // wave-uniform -> SALU loop control, s_load for off[]
        ix0 = __builtin_amdgcn_readfirstlane(ix0);
        ix1 = __builtin_amdgcn_readfirstlane(ix1);
        iy0 = __builtin_amdgcn_readfirstlane(iy0);
        iy1 = __builtin_amdgcn_readfirstlane(iy1);
        iz0 = __builtin_amdgcn_readfirstlane(iz0);
        iz1 = __builtin_amdgcn_readfirstlane(iz1);

        for (int cx = ix0; cx <= ix1; ++cx) {
            for (int cy = iy0; cy <= iy1; ++cy) {
                const int colbase = (cx * GY + cy) * GZ;
                const int s0 = __builtin_amdgcn_readfirstlane(off[colbase + iz0]);
                const int e0 = __builtin_amdgcn_readfirstlane(off[colbase + iz1 + 1]);
                for (int p0 = s0; p0 < e0; p0 += 64) {  // wave-uniform trip count
                    const int p = p0 + lane;
                    bool pl = false;
                    float4 pt;
                    if (p < e0) {
                        pt = pts4[p];
                        const float dx = qx - pt.x, dy = qy - pt.y, dz = qz - pt.z;
                        const float d2 = fmaf(dx, dx, fmaf(dy, dy, dz * dz));
                        pl = (d2 < tauL);
                    }
                    const unsigned long long mL = __ballot(pl);
                    if (pl) {
                        const int o = cntL + (int)__popcll(mL & ((1ULL << lane) - 1ULL));
                        if (o < CAP) s_c[wv][o] = pt;
                    }
                    cntL += (int)__popcll(mL);
                }
            }
        }
        if (cntL > CAP) { h *= 0.80f; continue; }       // overflow -> shrink

        // packed key: fp64 d2 bits, low 13 mantissa bits = id (keys unique)
        key = ~0ull;
        if (lane < cntL) {
            c4 = s_c[wv][lane];
            const double dx = (double)qx - (double)c4.x;
            const double dy = (double)qy - (double)c4.y;
            const double dz = (double)qz - (double)c4.z;
            const double d2 = fma(dx, dx, fma(dy, dy, dz * dz));
            key = (__double_as_longlong(d2) & ~IDMASK)
                | (unsigned long long)(unsigned)__float_as_int(c4.w);
        }
        const unsigned long long tauKey =
            (unsigned long long)__double_as_longlong((double)tau) & ~IDMASK;
        const int cntS = (int)__popcll(__ballot(key < tauKey));
        if (cntS >= 11) break;                          // wave-uniform
        h *= 1.35f;                                     // too few -> grow
    }
    cntL = min(cntL, CAP);                  // safety (attempt exhaustion only)

    // ---- rank-by-count: rank = #{keys < mine}; no dependent shuffle chain ----
    s_k[wv][lane] = key;
    int rank = 0;
    for (int c = 0; c < cntL; ++c)          // wave-uniform; broadcast ds_read
        rank += (s_k[wv][c] < key) ? 1 : 0;
    // real lanes get unique ranks 0..cntL-1; pad lanes rank >= cntL >= 11.

    if (isq) {
        // p0 = rank-0 candidate; edges = ranks 1..10 (set-min, order-free)
        const unsigned long long m0 = __ballot(rank == 0);
        const int l0 = (int)__ffsll(m0) - 1;
        const float p0x = __shfl(c4.x, l0, 64);
        const float p0y = __shfl(c4.y, l0, 64);
        const float p0z = __shfl(c4.z, l0, 64);
        float sq = INFINITY;
        if (rank >= 1 && rank <= 10) {
            const float ex = c4.x - p0x, ey = c4.y - p0y, ez = c4.z - p0z;
            const float el = sqrtf(ex * ex + ey * ey + ez * ez);
            const float px = qx - p0x, py = qy - p0y, pz = qz - p0z;
            const float vl = (px * ex + py * ey + pz * ez) / el;
            const float t  = vl - 0.5f * el;
            sq = t * t;
        }
        #pragma unroll
        for (int s = 32; s > 0; s >>= 1) sq = fminf(sq, __shfl_xor(sq, s, 64));
        if (lane == 0) out[row] = sq;
    } else {
        if (rank >= 1 && rank <= 10) {
            const double d2s = __longlong_as_double((long long)(key & ~IDMASK));
            out[Nq + outj * 10 + (rank - 1)] = expf(-100.0f * (float)d2s) / 100.0f;
        }
    }
}

extern "C" void kernel_launch(void* const* d_in, const int* in_sizes, int n_in,
                              void* d_out, int out_size, void* d_ws, size_t ws_size,
                              hipStream_t stream) {
    const float* queries = (const float*)d_in[0];
    const float* vpoints = (const float*)d_in[1];
    float* out = (float*)d_out;
    const int Nq = in_sizes[0] / 3;
    const int Mv = in_sizes[1] / 3;

    // workspace layout: pts4[Mv] | off[NCELL+1] | cur[NCELL]
    char* base = (char*)d_ws;
    float4* pts4 = (float4*)base;
    int* off = (int*)(base + (size_t)Mv * sizeof(float4));
    int* cur = off + NCELL + 1;

    k_histscan<<<1, BUILD_T, 0, stream>>>(vpoints, off, cur, Mv);
    k_scatter<<<(Mv + 255) / 256, 256, 0, stream>>>(vpoints, cur, pts4, Mv);

    const int total_rows = Nq + Mv;
    const int blocks = (total_rows + WPB - 1) / WPB;
    voronoi_kernel<<<blocks, BLOCK_T, 0, stream>>>(queries, pts4, off,
                                                   out, Nq, Mv);
}